// Round 12
// baseline (140.884 us; speedup 1.0000x reference)
//
#include <hip/hip_runtime.h>
#include <stdint.h>

#define EPSN 1e-12f

typedef float f32x16 __attribute__((ext_vector_type(16)));
typedef float f32x4 __attribute__((ext_vector_type(4)));
typedef __bf16 bf16x8 __attribute__((ext_vector_type(8)));

// ---- bf16 helpers (round-to-nearest-even) ----
__device__ __forceinline__ unsigned short f2bf(float f) {
  union { float f; unsigned int u; } v; v.f = f;
  unsigned int u = v.u + 0x7FFFu + ((v.u >> 16) & 1u);
  return (unsigned short)(u >> 16);
}

// ---- workspace layout (ushort offsets) ----
// Fragment-major packed weights for 32x32x16 MFMA:
//   addr = ((tile*18 + ks)*64 + lane)*8 + j
//   value = W[o = tile*32 + (lane&31)][k = ks*16 + (lane>>5)*8 + j]
//   (k=258 bias, >258 zero). Per-lane 16B load at base+lane*16: coalesced 1KB.
#define WQF_OFF 0
#define WKF_OFF (32 * 18 * 64 * 8)
#define WVP_OFF (2 * 32 * 18 * 64 * 8)

// =====================================================================
// prep (R10 version): coalesced pack + parallel WVt
// =====================================================================
__global__ __launch_bounds__(256) void prep_kernel(
    const float* __restrict__ wq, const float* __restrict__ bq,
    const float* __restrict__ wk, const float* __restrict__ bk,
    const float* __restrict__ v, const float* __restrict__ wout,
    unsigned short* __restrict__ wsp) {
  int bid = blockIdx.x;
  if (bid < 512) {
    int isK = bid >= 256;
    int ob = (bid & 255) * 4;
    const float* w = isK ? wk : wq;
    const float* bb = isK ? bk : bq;
    unsigned short* dst = wsp + (isK ? WKF_OFF : WQF_OFF);
    for (int i = threadIdx.x; i < 4 * 129; i += 256) {
      int r = i / 129, q = i - r * 129;
      int o = ob + r, k = q * 2;
      float2 w2 = *(const float2*)(w + o * 258 + k);
      int g = o >> 5, col = o & 31;
      int ks = k >> 4, hi = (k >> 3) & 1, j = k & 7;
      uint32_t pk = (uint32_t)f2bf(w2.x) | ((uint32_t)f2bf(w2.y) << 16);
      *(uint32_t*)(dst + (((g * 18 + ks) * 64 + hi * 32 + col) << 3) + j) = pk;
    }
    for (int i = threadIdx.x; i < 4 * 30; i += 256) {
      int r = i / 30, kk = 258 + (i - r * 30);
      int o = ob + r;
      int g = o >> 5, col = o & 31;
      int ks = kk >> 4, hi = (kk >> 3) & 1, j = kk & 7;
      dst[(((g * 18 + ks) * 64 + hi * 32 + col) << 3) + j] =
          (kk == 258) ? f2bf(bb[o]) : (unsigned short)0;
    }
  } else {
    int idx = (bid - 512) * 256 + threadIdx.x;
    int fc = idx & 15, m = (idx >> 4) & 63, o = idx >> 10;
    const f32x4* wo = (const f32x4*)(wout + o * 256 + fc * 16);
    const f32x4* vm = (const f32x4*)(v + m * 256 + fc * 16);
    float s = 0.f;
#pragma unroll
    for (int f = 0; f < 4; ++f) {
      f32x4 a = wo[f], bvv = vm[f];
      s += a[0]*bvv[0] + a[1]*bvv[1] + a[2]*bvv[2] + a[3]*bvv[3];
    }
    s += __shfl_xor(s, 1, 64);
    s += __shfl_xor(s, 2, 64);
    s += __shfl_xor(s, 4, 64);
    s += __shfl_xor(s, 8, 64);
    if (fc == 0) wsp[WVP_OFF + o * 64 + m] = f2bf(s);
  }
}

// =====================================================================
// fused R12: merged single-pass q+k. 32 px/block, 512 blocks, 16 waves.
// Wave w: q-tiles (2w,2w+1) AND k-tiles (2w,2w+1) -> 4 independent MFMA
// chains per B-read; B in fragment-sequential LDS (conflict-free b128);
// direct coalesced A loads, zero asm fences, zero K-loop barriers.
// C/D (verified): col=lane&31(px), row rr=(r&3)+8*((r>>2)&1)+16*(r>>3)+4*q2;
// o-row = tile*32+rr = m*16+j -> m = 2*tile + (r>=8), j = rr&15.
// =====================================================================
#define QSS 33   // qbar row stride (floats)
#define AT 72    // attnM row stride (shorts)

__global__ __launch_bounds__(1024, 4) void fused_kernel(
    const float* __restrict__ x, const float* __restrict__ pos,
    const unsigned short* __restrict__ wsp, const float* __restrict__ bout,
    float* __restrict__ out) {
  // xpF[((ks*2+q2)*32 + px)*8 + jj] = bf16(channel c = ks*16+q2*8+jj, pixel px)
  // -> a wave's B-read is lane i @ base+16*i : bank-sequential, conflict-free.
  __shared__ __align__(16) unsigned short xpF[18 * 2 * 32 * 8];  // 18432 B
  __shared__ __align__(16) float qbarL[16 * QSS];                // 2112 B
  __shared__ __align__(16) unsigned short attnM[32 * AT];        // 4608 B
  __shared__ float boutL[256];                                   // 1024 B

  const int tid = threadIdx.x;
  const int lane = tid & 63;
  const int wid = __builtin_amdgcn_readfirstlane(tid >> 6);
  const int px = lane & 31, q2 = lane >> 5;
  const int P0 = blockIdx.x * 32;
  const int b = P0 >> 12, s0 = P0 & 4095;

  // ---- stage xpF: c-major global reads (32 consecutive px per half-wave) ----
  uint32_t* xp32 = (uint32_t*)xpF;
  for (int i = tid; i < 32 * 144; i += 1024) {
    int p = i & 31, dcol = i >> 5;   // c0 = 2*dcol, covers c 0..287
    int c0 = dcol * 2;
    float v0, v1;
    if (c0 < 256) {
      v0 = x[(b * 256 + c0) * 4096 + s0 + p];
      v1 = x[(b * 256 + c0 + 1) * 4096 + s0 + p];
    } else if (c0 == 256) {
      v0 = pos[s0 + p];
      v1 = pos[4096 + s0 + p];
    } else {
      v0 = (c0 == 258) ? 1.0f : 0.0f;   // bias channel at 258
      v1 = 0.0f;
    }
    // dword index: ((c0>>3)*32 + p)*4 + ((c0&7)>>1) = (dcol>>2)*128 + p*4 + (dcol&3)
    xp32[(dcol >> 2) * 128 + p * 4 + (dcol & 3)] =
        (uint32_t)f2bf(v0) | ((uint32_t)f2bf(v1) << 16);
  }
  if (tid < 256) boutL[tid] = bout[tid];
  if (tid < 16 * QSS) qbarL[tid] = 0.f;
  __syncthreads();

  // ================= merged q+k K-loop =================
  const unsigned short* aq = wsp + WQF_OFF + (2 * wid) * 18 * 512 + lane * 8;
  const unsigned short* ak = wsp + WKF_OFF + (2 * wid) * 18 * 512 + lane * 8;

  f32x16 accq0 = (f32x16)0.f, accq1 = (f32x16)0.f,
         acck0 = (f32x16)0.f, acck1 = (f32x16)0.f;
#pragma unroll 3
  for (int ks = 0; ks < 18; ++ks) {
    bf16x8 bv = *(const bf16x8*)&xpF[(ks * 2 + q2) * 256 + px * 8];
    bf16x8 aq0 = *(const bf16x8*)(aq + ks * 512);
    bf16x8 aq1 = *(const bf16x8*)(aq + 9216 + ks * 512);
    bf16x8 ak0 = *(const bf16x8*)(ak + ks * 512);
    bf16x8 ak1 = *(const bf16x8*)(ak + 9216 + ks * 512);
    accq0 = __builtin_amdgcn_mfma_f32_32x32x16_bf16(aq0, bv, accq0, 0, 0, 0);
    accq1 = __builtin_amdgcn_mfma_f32_32x32x16_bf16(aq1, bv, accq1, 0, 0, 0);
    acck0 = __builtin_amdgcn_mfma_f32_32x32x16_bf16(ak0, bv, acck0, 0, 0, 0);
    acck1 = __builtin_amdgcn_mfma_f32_32x32x16_bf16(ak1, bv, acck1, 0, 0, 0);
  }

  // ---- normalize q per m, accumulate qbar partials ----
  {
    float qsum[8];
#pragma unroll
    for (int r = 0; r < 8; ++r) qsum[r] = 0.f;
#pragma unroll
    for (int t = 0; t < 2; ++t) {
      const f32x16 a = t ? accq1 : accq0;
      float s20 = 0.f, s21 = 0.f;
#pragma unroll
      for (int r = 0; r < 8; ++r) {
        s20 = fmaf(a[r], a[r], s20);
        s21 = fmaf(a[r + 8], a[r + 8], s21);
      }
      s20 += __shfl_xor(s20, 32, 64);
      s21 += __shfl_xor(s21, 32, 64);
      float i0 = 1.0f / fmaxf(sqrtf(s20), EPSN);
      float i1 = 1.0f / fmaxf(sqrtf(s21), EPSN);
#pragma unroll
      for (int r = 0; r < 8; ++r) qsum[r] += a[r] * i0 + a[r + 8] * i1;
    }
#pragma unroll
    for (int r = 0; r < 8; ++r) {
      int j = (r & 3) + ((r >> 2) << 3) + (q2 << 2);
      atomicAdd(&qbarL[j * QSS + px], qsum[r] * (1.0f / 64.0f));
    }
  }
  __syncthreads();  // all qbar contributions visible

  // ---- attn: normalize k, dot with qbar ----
  {
    float qb[8];
#pragma unroll
    for (int r = 0; r < 8; ++r) {
      int j = (r & 3) + ((r >> 2) << 3) + (q2 << 2);
      qb[r] = qbarL[j * QSS + px];
    }
#pragma unroll
    for (int t = 0; t < 2; ++t) {
      const f32x16 a = t ? acck1 : acck0;
      float s20 = 0.f, s21 = 0.f, sp0 = 0.f, sp1 = 0.f;
#pragma unroll
      for (int r = 0; r < 8; ++r) {
        s20 = fmaf(a[r], a[r], s20);         sp0 = fmaf(qb[r], a[r], sp0);
        s21 = fmaf(a[r + 8], a[r + 8], s21); sp1 = fmaf(qb[r], a[r + 8], sp1);
      }
      s20 += __shfl_xor(s20, 32, 64);
      s21 += __shfl_xor(s21, 32, 64);
      sp0 += __shfl_xor(sp0, 32, 64);
      sp1 += __shfl_xor(sp1, 32, 64);
      if (q2 == 0) {
        int m0 = wid * 4 + t * 2;   // k-tile 2w+t -> m = 2*(2w+t) + {0,1}
        attnM[px * AT + m0]     = f2bf(sp0 / fmaxf(sqrtf(s20), EPSN));
        attnM[px * AT + m0 + 1] = f2bf(sp1 / fmaxf(sqrtf(s21), EPSN));
      }
    }
  }
  __syncthreads();

  // ================= epilogue: out = x + bout + WVt @ attn =================
  if (wid < 8) {
    f32x16 e = (f32x16)0.f;
    const unsigned short* wv = wsp + WVP_OFF + (wid * 32 + px) * 64 + q2 * 8;
    const unsigned short* ab = &attnM[px * AT + q2 * 8];
#pragma unroll
    for (int ks = 0; ks < 4; ++ks) {
      bf16x8 av = *(const bf16x8*)(wv + ks * 16);
      bf16x8 bv = *(const bf16x8*)(ab + ks * 16);
      e = __builtin_amdgcn_mfma_f32_32x32x16_bf16(av, bv, e, 0, 0, 0);
    }
#pragma unroll
    for (int r = 0; r < 16; ++r) {
      const int o = wid * 32 + (r & 3) + (((r >> 2) & 1) << 3) + (q2 << 2) + ((r >> 3) << 4);
      const int gi = (b * 256 + o) * 4096 + s0 + px;
      out[gi] = x[gi] + boutL[o] + e[r];
    }
  }
}

// =====================================================================
extern "C" void kernel_launch(void* const* d_in, const int* in_sizes, int n_in,
                              void* d_out, int out_size, void* d_ws, size_t ws_size,
                              hipStream_t stream) {
  const float* x    = (const float*)d_in[0];
  const float* pos  = (const float*)d_in[1];
  const float* wq   = (const float*)d_in[2];
  const float* bq   = (const float*)d_in[3];
  const float* wk   = (const float*)d_in[4];
  const float* bk   = (const float*)d_in[5];
  const float* v    = (const float*)d_in[6];
  const float* wout = (const float*)d_in[7];
  const float* bout = (const float*)d_in[8];
  float* out = (float*)d_out;
  unsigned short* wsp = (unsigned short*)d_ws;

  hipLaunchKernelGGL(prep_kernel, dim3(1536), dim3(256), 0, stream,
                     wq, bq, wk, bk, v, wout, wsp);
  hipLaunchKernelGGL(fused_kernel, dim3(512), dim3(1024), 0, stream,
                     x, pos, wsp, bout, out);
}